// Round 1
// baseline (77.467 us; speedup 1.0000x reference)
//
#include <hip/hip_runtime.h>
#include <math.h>

// Problem constants (from reference): L=13, M=12, ODD_KS=(1,3,5) -> NK=3
#define LL   13
#define MM   12
#define NKK  3
#define BLOCK 256
#define HALO  24                 // window spans [t-24, t+24]
#define WIN  (BLOCK + 2*HALO)    // 304 samples staged per block

// Per output (b,t):
//   x1(l)      = xc[(t + l - 12) % T]           (LDS idx: tid + l + 12)
//   p2 samples = xc[(t + l + m - 24) % T], m<M  (LDS idx: tid + l + m)
//   x3_last(l) = xc[(t + l + 12) % T]           (LDS idx: tid + l + 36)
//   p3 samples = xc[(t + l + m) % T], m<M       (LDS idx: tid + l + m + 24)
//   out = sum_l x1*(A.p1 + sum_m B[l,m,:].p2) + x3_last*(sum_m C[l,m,:].p3)

__global__ __launch_bounds__(BLOCK)
void gmp_kernel(const float* __restrict__ x,    // (B,T,2)
                const float* __restrict__ Ac,   // (L,NK)
                const float* __restrict__ Bc,   // (L,M,NK)
                const float* __restrict__ Cc,   // (L,M,NK)
                float* __restrict__ out,        // (B,T,2)
                int T, int tilesPerB)
{
    __shared__ float s_re[WIN], s_im[WIN], s_a1[WIN], s_a3[WIN], s_a5[WIN];

    const int tid = threadIdx.x;
    const int b   = blockIdx.x / tilesPerB;
    const int t0  = (blockIdx.x % tilesPerB) * BLOCK;

    const float* xb = x + (size_t)b * T * 2;

    // Stage window [t0-HALO, t0+BLOCK+HALO) with circular wrap, precompute odd powers
    for (int i = tid; i < WIN; i += BLOCK) {
        int t = t0 - HALO + i;
        if (t < 0)  t += T;
        if (t >= T) t -= T;
        float re = xb[2 * t], im = xb[2 * t + 1];
        float a2 = re * re + im * im;
        float a  = sqrtf(a2);
        s_re[i] = re;
        s_im[i] = im;
        s_a1[i] = a;
        s_a3[i] = a * a2;
        s_a5[i] = a * a2 * a2;
    }
    __syncthreads();

    // Per-tap coefficient accumulators
    float cB[LL], cC[LL];
    #pragma unroll
    for (int l = 0; l < LL; ++l) {
        const int i1 = tid + l + 12;            // |x1| powers
        cB[l] = Ac[l * NKK + 0] * s_a1[i1]
              + Ac[l * NKK + 1] * s_a3[i1]
              + Ac[l * NKK + 2] * s_a5[i1];
        cC[l] = 0.0f;
    }

    // d = l + m in [0, 23]; fetch each power triple once per d
    #pragma unroll
    for (int d = 0; d < LL + MM - 1; ++d) {     // 0..23 (l<=12, m<=11)
        const int j  = tid + d;                 // powers for B-term (offset d-24)
        const float pa = s_a1[j], p3 = s_a3[j], p5 = s_a5[j];
        const int jc = j + HALO;                // powers for C-term (offset d)
        const float qa = s_a1[jc], q3 = s_a3[jc], q5 = s_a5[jc];
        #pragma unroll
        for (int l = 0; l < LL; ++l) {
            const int m = d - l;
            if (m >= 0 && m < MM) {             // compile-time resolved under unroll
                const float* bp = Bc + (l * MM + m) * NKK;
                cB[l] += bp[0] * pa + bp[1] * p3 + bp[2] * p5;
                const float* cp = Cc + (l * MM + m) * NKK;
                cC[l] += cp[0] * qa + cp[1] * q3 + cp[2] * q5;
            }
        }
    }

    // Complex epilogue: sum_l x1*cB[l] + x3_last*cC[l]
    float sr = 0.0f, si = 0.0f;
    #pragma unroll
    for (int l = 0; l < LL; ++l) {
        const int i1 = tid + l + 12;
        sr += s_re[i1] * cB[l];
        si += s_im[i1] * cB[l];
        const int i3 = tid + l + 36;
        sr += s_re[i3] * cC[l];
        si += s_im[i3] * cC[l];
    }

    const int t = t0 + tid;
    if (t < T) {
        out[((size_t)b * T + t) * 2 + 0] = sr;
        out[((size_t)b * T + t) * 2 + 1] = si;
    }
}

extern "C" void kernel_launch(void* const* d_in, const int* in_sizes, int n_in,
                              void* d_out, int out_size, void* d_ws, size_t ws_size,
                              hipStream_t stream)
{
    // Inputs (setup_inputs order): x (B,T,2) f32, h_0 (B,16) f32 [unused],
    // A_kl (L,NK) f32, B_klm (L,M,NK) f32, C_klm (L,M,NK) f32
    const float* x  = (const float*)d_in[0];
    const float* Ac = (const float*)d_in[2];
    const float* Bc = (const float*)d_in[3];
    const float* Cc = (const float*)d_in[4];
    float* out = (float*)d_out;

    const int Bsz = in_sizes[1] / 16;                 // h_0 is (B,16)
    const int T   = in_sizes[0] / (2 * Bsz);          // x is (B,T,2)
    const int tilesPerB = (T + BLOCK - 1) / BLOCK;    // 32 for T=8192

    dim3 grid(Bsz * tilesPerB);
    dim3 block(BLOCK);
    gmp_kernel<<<grid, block, 0, stream>>>(x, Ac, Bc, Cc, out, T, tilesPerB);
}

// Round 2
// 73.944 us; speedup vs baseline: 1.0476x; 1.0476x over previous
//
#include <hip/hip_runtime.h>
#include <math.h>

// Problem constants (from reference): L=13, M=12, ODD_KS=(1,3,5) -> NK=3
#define LL   13
#define MM   12
#define NKK  3
#define BLOCK 256
#define HALO  24                 // window spans [t-24, t+24]
#define WIN  (BLOCK + 2*HALO)    // 304 samples staged per block

// Per output (b,t), with LDS window base t0-24:
//   x1(l)      = xc[t + l - 12]   -> Z[tid + l + 12]
//   B-powers   = P[tid + l + m]        (m in [0,12))
//   x3_last(l) = xc[t + l + 12]   -> Z[tid + l + 36]
//   C-powers   = P[tid + l + m + 24]
// out = sum_l x1*(A[l].p1 + sum_m B[l,m].P) + x3last*(sum_m C[l,m].P')

__global__ __launch_bounds__(BLOCK)
void gmp_kernel(const float* __restrict__ x,    // (B,T,2)
                const float* __restrict__ Ac,   // (L,NK)
                const float* __restrict__ Bc,   // (L,M,NK)
                const float* __restrict__ Cc,   // (L,M,NK)
                float* __restrict__ out,        // (B,T,2)
                int T, int tilesPerB)
{
    __shared__ float4 sP[WIN];   // {a^1, a^3, a^5, 0} -> one ds_read_b128
    __shared__ float2 sZ[WIN];   // {re, im}           -> one ds_read_b64

    const int tid = threadIdx.x;
    const int b   = blockIdx.x / tilesPerB;
    const int t0  = (blockIdx.x % tilesPerB) * BLOCK;

    const float* xb = x + (size_t)b * T * 2;

    // Stage window [t0-HALO, t0+BLOCK+HALO) with circular wrap; powers once per sample
    for (int i = tid; i < WIN; i += BLOCK) {
        int t = t0 - HALO + i;
        if (t < 0)  t += T;
        if (t >= T) t -= T;
        float re = xb[2 * t], im = xb[2 * t + 1];
        float a2 = re * re + im * im;
        float a  = sqrtf(a2);
        sZ[i] = make_float2(re, im);
        sP[i] = make_float4(a, a * a2, a * a2 * a2, 0.0f);
    }
    __syncthreads();

    // Per-tap coefficient accumulators (compile-time indexed -> registers)
    float cB[LL], cC[LL];
    #pragma unroll
    for (int l = 0; l < LL; ++l) {
        const float4 p = sP[tid + l + 12];          // |x1| powers
        cB[l] = Ac[l * NKK + 0] * p.x
              + Ac[l * NKK + 1] * p.y
              + Ac[l * NKK + 2] * p.z;
        cC[l] = 0.0f;
    }

    // d = l + m in [0,23]; one b128 power fetch per d per term.
    // Fully unrolled: every coefficient offset is a compile-time constant
    // -> wave-uniform s_load broadcasts, zero VALU address math.
    #pragma unroll
    for (int d = 0; d < LL + MM - 1; ++d) {
        const float4 p = sP[tid + d];               // B-term powers (offset d-24)
        const float4 q = sP[tid + d + HALO];        // C-term powers (offset d)
        #pragma unroll
        for (int l = 0; l < LL; ++l) {
            const int m = d - l;
            if (m >= 0 && m < MM) {                 // folds at compile time
                const float* bp = Bc + (l * MM + m) * NKK;
                cB[l] += bp[0] * p.x + bp[1] * p.y + bp[2] * p.z;
                const float* cp = Cc + (l * MM + m) * NKK;
                cC[l] += cp[0] * q.x + cp[1] * q.y + cp[2] * q.z;
            }
        }
    }

    // Complex epilogue: sum_l x1*cB[l] + x3_last*cC[l]
    float sr = 0.0f, si = 0.0f;
    #pragma unroll
    for (int l = 0; l < LL; ++l) {
        const float2 z1 = sZ[tid + l + 12];
        const float2 z3 = sZ[tid + l + 36];
        sr += z1.x * cB[l] + z3.x * cC[l];
        si += z1.y * cB[l] + z3.y * cC[l];
    }

    const int t = t0 + tid;
    if (t < T) {
        out[((size_t)b * T + t) * 2 + 0] = sr;
        out[((size_t)b * T + t) * 2 + 1] = si;
    }
}

extern "C" void kernel_launch(void* const* d_in, const int* in_sizes, int n_in,
                              void* d_out, int out_size, void* d_ws, size_t ws_size,
                              hipStream_t stream)
{
    // Inputs (setup_inputs order): x (B,T,2) f32, h_0 (B,16) f32 [unused],
    // A_kl (L,NK) f32, B_klm (L,M,NK) f32, C_klm (L,M,NK) f32
    const float* x  = (const float*)d_in[0];
    const float* Ac = (const float*)d_in[2];
    const float* Bc = (const float*)d_in[3];
    const float* Cc = (const float*)d_in[4];
    float* out = (float*)d_out;

    const int Bsz = in_sizes[1] / 16;                 // h_0 is (B,16)
    const int T   = in_sizes[0] / (2 * Bsz);          // x is (B,T,2)
    const int tilesPerB = (T + BLOCK - 1) / BLOCK;    // 32 for T=8192

    dim3 grid(Bsz * tilesPerB);
    dim3 block(BLOCK);
    gmp_kernel<<<grid, block, 0, stream>>>(x, Ac, Bc, Cc, out, T, tilesPerB);
}